// Round 9
// baseline (12514.906 us; speedup 1.0000x reference)
//
#include <hip/hip_runtime.h>

// Packed-LSTM (B=64, S=2048, H=512, V=25) + final linear head.
// QUAD-STAGGER: 64 WGs x 256 thr; 4 sets x 16 WGs. Set s owns sorted ranks
// [16s,16s+16); group i (i=0..3) = local ranks {i,4+i,8+i,12+i} (4 batches,
// near-equal lengths; group 0 longest). Each WG owns 32 hidden units (128
// gate rows) of ALL 4 groups; W_hh B-fragments (VGPR) and xgt shared.
// Round t = 4 phases; phase i: {vmcnt-check prefetched tags -> stage ->
// MFMA[16x512]@[512x128] (12 zero A-rows) -> prefetch group (i+2)&3 ->
// cell+store}. Symmetric 2-phase store->issue and issue->check gaps hide
// the agent-scope visibility latency for EVERY group (fixes R8's asymmetry
// where one group's prefetch always sampled too early).
//
// Exchange: 16-bit-tagged dwords ((t&0xFFFF)<<16 | bf16(h)) through LLC,
// wave-coalesced (producer w: dwords w*128..w*128+127). Consumer prefetch =
// 4 inline-asm global_load_dwordx2 sc0 sc1 (pinned, bypass stale L1/L2);
// check = s_waitcnt vmcnt(0) + sched_barrier + tag compare; mismatch ->
// agent-scope spin (always-correct fallback). Parity double buffer; 2-deep
// pipeline bound prevents overwrite races (a WG stores t+2 only after its
// check of t+1 OK => all WGs stored t+1 => all consumed t).

#define VOCAB 25
#define HIDDEN 512
#define BATCH 64
#define SEQ 2048
#define NSETS 4
#define HSL 32
#define RWG 128
#define NTHREADS 256
#define GDW 2048  // dwords per (set,group,parity) buffer = 16 WGs * 128

typedef short s16x8 __attribute__((ext_vector_type(8)));
typedef float f32x4 __attribute__((ext_vector_type(4)));
typedef unsigned long long ull;
typedef unsigned short ushort_t;

__device__ inline unsigned short f2bf(float x) {
  unsigned u = __float_as_uint(x);
  u += 0x7fffu + ((u >> 16) & 1u);  // RNE
  return (unsigned short)(u >> 16);
}
__device__ inline float sigf(float x) { return 1.0f / (1.0f + __expf(-x)); }
__device__ inline float tanh_fast(float x) { return 2.0f / (1.0f + __expf(-2.0f * x)) - 1.0f; }

__global__ void prep_kernel(unsigned* hg, float* out) {
  const int i0 = blockIdx.x * blockDim.x + threadIdx.x;
  const int n = blockDim.x * gridDim.x;
  for (int k = i0; k < 2 * NSETS * 4 * GDW; k += n) hg[k] = 0u;  // tag 0 never matches
  if (i0 < BATCH) out[i0] = 0.f;
}

__global__ __launch_bounds__(NTHREADS, 1) void lstm_persistent(
    const int* __restrict__ tokens, const int* __restrict__ lengths,
    const float* __restrict__ W_ih, const float* __restrict__ W_hh,
    const float* __restrict__ b_ih, const float* __restrict__ b_hh,
    const float* __restrict__ fc_w, const float* __restrict__ fc_b,
    float* __restrict__ out, unsigned* hg) {
  const int tid = threadIdx.x;
  const int bid = blockIdx.x;
  // XCD-aware: set s uses blocks with bid%8 in {2s,2s+1} -> 2 XCDs/set.
  const int x = bid & 7;
  const int s = x >> 1;                       // set 0..3
  const int w = ((bid >> 3) << 1) | (x & 1);  // wg-in-set 0..15

  __shared__ __align__(16) ushort_t hbuf[4][16][HIDDEN + 8];  // per-group; rows 4-15 stay 0
  __shared__ float gatesb[4][4][RWG + 5];
  __shared__ float xgt[VOCAB][RWG + 5];
  __shared__ int lenAll[BATCH];
  __shared__ int order_[BATCH];
  __shared__ int gIdxS[16];
  __shared__ int gLenS[16];

  if (tid < BATCH) lenAll[tid] = lengths[tid];
  __syncthreads();
  if (tid < BATCH) {  // stable argsort(-lengths): rank by count
    const int L = lenAll[tid];
    int r = 0;
    for (int jx = 0; jx < BATCH; ++jx) {
      const int lj = lenAll[jx];
      r += ((lj > L) || (lj == L && jx < tid)) ? 1 : 0;
    }
    order_[r] = tid;
  }
  __syncthreads();
  if (tid < 16) {
    const int oi = order_[s * 16 + tid];
    gIdxS[tid] = oi;
    gLenS[tid] = lenAll[oi];
  }
  for (int i = tid; i < 4 * 16 * (HIDDEN + 8); i += NTHREADS)
    ((ushort_t*)hbuf)[i] = 0;  // h0 = 0; A-rows 4-15 permanently zero
  for (int i = tid; i < VOCAB * RWG; i += NTHREADS) {
    const int v = i / RWG, rl = i % RWG;
    const int rg = (rl >> 5) * HIDDEN + w * HSL + (rl & 31);
    xgt[v][rl] = W_ih[rg * VOCAB + v] + b_ih[rg] + b_hh[rg];
  }
  __syncthreads();

  int TGa[4];
#pragma unroll
  for (int i = 0; i < 4; ++i) TGa[i] = gLenS[i];  // group max = local rank i (sorted)
  const int T = TGa[0];

  const int lane = tid & 63;
  const int wv = tid >> 6;
  const int m16 = lane & 15;
  const int quad = lane >> 4;

  // B fragments (bf16 W_hh slice) in VGPRs: wave wv owns ntiles {wv, wv+4}.
  s16x8 Bf[2][16];
#pragma unroll
  for (int nti = 0; nti < 2; ++nti) {
    const int nt = wv + 4 * nti;
    const int rl = nt * 16 + m16;  // local gate-row 0..127
    const int rg = (rl >> 5) * HIDDEN + w * HSL + (rl & 31);
    const float* wr = W_hh + (size_t)rg * HIDDEN;
#pragma unroll
    for (int kt = 0; kt < 16; ++kt) {
      const float* p = wr + kt * 32 + quad * 8;
#pragma unroll
      for (int e = 0; e < 8; ++e) Bf[nti][kt][e] = (short)f2bf(p[e]);
    }
  }

  // Cell mapping: threads 0..127; thread owns unit j of batch cb, per group.
  const int cb = (tid >> 5) & 3;
  const int j = tid & 31;
  const bool cellTh = tid < 128;
  const int* tokR[4];
  int myLen[4];
#pragma unroll
  for (int i = 0; i < 4; ++i) {
    const int lr = 4 * cb + i;  // local rank of (group i, batch cb)
    const int gi = gIdxS[lr];
    tokR[i] = tokens + (size_t)gi * SEQ;
    myLen[i] = gLenS[lr];
  }

  ull qG[4][4];  // prefetched tagged qwords, per group
  float cS[4] = {0.f, 0.f, 0.f, 0.f};
  float hS[4] = {0.f, 0.f, 0.f, 0.f};
  const unsigned voA = (unsigned)(tid * 8);
  const unsigned voB = voA + 4096u;

  for (int t = 0; t < T; ++t) {
    const unsigned tu = (unsigned)t;
#pragma unroll
    for (int i = 0; i < 4; ++i) {
      const bool alive = (t < TGa[i]);
      if (alive) {
        if (t > 0) {
          asm volatile("s_waitcnt vmcnt(0)" ::: "memory");
          __builtin_amdgcn_sched_barrier(0);
          bool ok = true;
#pragma unroll
          for (int r = 0; r < 4; ++r) {
            ok &= (((unsigned)(qG[i][r] >> 16) & 0xFFFFu) == tu);
            ok &= (((unsigned)(qG[i][r] >> 48)) == tu);
          }
          if (!ok) {  // stale prefetch -> agent-scope spin (always correct)
            const ull* src =
                (const ull*)(hg + (size_t)(((t & 1) * NSETS + s) * 4 + i) * GDW) + tid;
            for (;;) {
#pragma unroll
              for (int r = 0; r < 4; ++r)
                qG[i][r] = __hip_atomic_load(src + r * 256, __ATOMIC_RELAXED,
                                             __HIP_MEMORY_SCOPE_AGENT);
              ok = true;
#pragma unroll
              for (int r = 0; r < 4; ++r) {
                ok &= (((unsigned)(qG[i][r] >> 16) & 0xFFFFu) == tu);
                ok &= (((unsigned)(qG[i][r] >> 48)) == tu);
              }
              if (ok) break;
            }
          }
          // stage: qword r = dwords d0,d0+1; d0 = 2*(tid+256r)
#pragma unroll
          for (int r = 0; r < 4; ++r) {
            const int d0 = 2 * (tid + 256 * r);
            const int wsrc = d0 >> 7;
            const int bq = (d0 >> 5) & 3;
            const int ju = d0 & 31;
            const unsigned lo = (unsigned)qG[i][r] & 0xFFFFu;
            const unsigned hi = (unsigned)(qG[i][r] >> 32) & 0xFFFFu;
            *(unsigned*)&hbuf[i][bq][wsrc * 32 + ju] = lo | (hi << 16);
          }
        }
        __syncthreads();  // hbuf[i] staged
        // gates = h[16x512]@Wslice^T[512x128]; A rows 4-15 zero
        f32x4 a0a = {0.f, 0.f, 0.f, 0.f}, a0b = {0.f, 0.f, 0.f, 0.f};
        f32x4 a1a = {0.f, 0.f, 0.f, 0.f}, a1b = {0.f, 0.f, 0.f, 0.f};
#pragma unroll
        for (int kt = 0; kt < 16; kt += 2) {
          const s16x8 A0 = *(const s16x8*)&hbuf[i][m16][kt * 32 + quad * 8];
          const s16x8 A1 = *(const s16x8*)&hbuf[i][m16][(kt + 1) * 32 + quad * 8];
          a0a = __builtin_amdgcn_mfma_f32_16x16x32_bf16(A0, Bf[0][kt], a0a, 0, 0, 0);
          a1a = __builtin_amdgcn_mfma_f32_16x16x32_bf16(A0, Bf[1][kt], a1a, 0, 0, 0);
          a0b = __builtin_amdgcn_mfma_f32_16x16x32_bf16(A1, Bf[0][kt + 1], a0b, 0, 0, 0);
          a1b = __builtin_amdgcn_mfma_f32_16x16x32_bf16(A1, Bf[1][kt + 1], a1b, 0, 0, 0);
        }
        const f32x4 ac0 = a0a + a0b, ac1 = a1a + a1b;
        if (quad == 0) {  // D rows m=v (batches 0..3)
#pragma unroll
          for (int v = 0; v < 4; ++v) {
            gatesb[i][v][wv * 16 + m16] = ac0[v];
            gatesb[i][v][(wv + 4) * 16 + m16] = ac1[v];
          }
        }
        __syncthreads();  // gates ready
      }
      {  // prefetch for group (i+2)&3: symmetric 2-phase gaps both sides
        const int jg = (i + 2) & 3;
        const int tj = (i >= 2) ? (t + 1) : t;
        if (tj >= 1 && tj < TGa[jg]) {
          const unsigned* pb = hg + (size_t)(((tj & 1) * NSETS + s) * 4 + jg) * GDW;
          asm volatile(
              "global_load_dwordx2 %[a0], %[vA], %[b] sc0 sc1\n\t"
              "global_load_dwordx2 %[a1], %[vA], %[b] offset:2048 sc0 sc1\n\t"
              "global_load_dwordx2 %[a2], %[vB], %[b] sc0 sc1\n\t"
              "global_load_dwordx2 %[a3], %[vB], %[b] offset:2048 sc0 sc1"
              : [a0] "=&v"(qG[jg][0]), [a1] "=&v"(qG[jg][1]),
                [a2] "=&v"(qG[jg][2]), [a3] "=&v"(qG[jg][3])
              : [vA] "v"(voA), [vB] "v"(voB), [b] "s"(pb)
              : "memory");
        }
      }
      if (alive && cellTh) {  // cell + publish
        const int tok = tokR[i][t];
        const float pi = gatesb[i][cb][j] + xgt[tok][j];
        const float pf = gatesb[i][cb][32 + j] + xgt[tok][32 + j];
        const float pg = gatesb[i][cb][64 + j] + xgt[tok][64 + j];
        const float po = gatesb[i][cb][96 + j] + xgt[tok][96 + j];
        if (t < myLen[i]) {
          const float ii = sigf(pi), ff = sigf(pf), gg = tanh_fast(pg), oo = sigf(po);
          cS[i] = ff * cS[i] + ii * gg;
          hS[i] = oo * tanh_fast(cS[i]);
        }
        if (t + 1 < TGa[i]) {
          unsigned* dst = hg + (size_t)((((t + 1) & 1) * NSETS + s) * 4 + i) * GDW +
                          w * 128 + cb * 32 + j;
          __hip_atomic_store(dst, ((unsigned)(t + 1) << 16) | (unsigned)f2bf(hS[i]),
                             __ATOMIC_RELAXED, __HIP_MEMORY_SCOPE_AGENT);
        }
      }
    }
  }

  // out[rank] = h . fc_w + fc_b; rank of (group i, batch cb) = s*16 + 4cb + i
#pragma unroll
  for (int i = 0; i < 4; ++i) {
    float part = cellTh ? hS[i] * fc_w[w * HSL + j] : 0.f;
    part += __shfl_down(part, 16, 32);
    part += __shfl_down(part, 8, 32);
    part += __shfl_down(part, 4, 32);
    part += __shfl_down(part, 2, 32);
    part += __shfl_down(part, 1, 32);
    if (cellTh && j == 0) {
      if (w == 0) part += fc_b[0];
      atomicAdd(&out[s * 16 + 4 * cb + i], part);
    }
  }
}

extern "C" void kernel_launch(void* const* d_in, const int* in_sizes, int n_in,
                              void* d_out, int out_size, void* d_ws, size_t ws_size,
                              hipStream_t stream) {
  (void)in_sizes; (void)n_in; (void)out_size; (void)ws_size;
  const int* tokens = (const int*)d_in[0];
  const int* lengths = (const int*)d_in[1];
  const float* W_ih = (const float*)d_in[2];
  const float* W_hh = (const float*)d_in[3];
  const float* b_ih = (const float*)d_in[4];
  const float* b_hh = (const float*)d_in[5];
  const float* fc_w = (const float*)d_in[6];
  const float* fc_b = (const float*)d_in[7];
  float* out = (float*)d_out;
  unsigned* hglob = (unsigned*)d_ws;  // 256 KB: 4 sets x 4 groups x 2 parity x 8KB

  prep_kernel<<<32, 256, 0, stream>>>(hglob, out);
  lstm_persistent<<<64, NTHREADS, 0, stream>>>(tokens, lengths, W_ih, W_hh, b_ih, b_hh,
                                               fc_w, fc_b, out, hglob);
}

// Round 11
// 11548.743 us; speedup vs baseline: 1.0837x; 1.0837x over previous
//
#include <hip/hip_runtime.h>

// Packed-LSTM (B=64, S=2048, H=512, V=25) + final linear head.
// QUAD-STAGGER, LDS-LANDED PREFETCH. 64 WGs x 256 thr; 4 sets x 16 WGs; set
// s owns sorted ranks [16s,16s+16) split into 4 groups of 4 consecutive
// ranks. Each WG owns 32 hidden units (128 gate rows) of all 4 groups;
// hbuf is ONE 16-row A-matrix (row 4g+cb = group g batch cb, each group at
// its own step); one MFMA per phase, D-rows of group I extracted by quad==I.
//
// Schedule per round t (phases I=0..3): [counted vmcnt -> tag-check LDS
// zone -> (spin fallback) -> repack zone->hbuf -> bar -> MFMA -> bar ->
// issue global_load_lds for group (I+2)&3 -> cell+store]. Raw s_barrier
// (no vmcnt drain) + counted vmcnt(6) keep prefetches in flight across
// phases (T3/T4 mechanism, m201-proven with this exact builtin).
//
// Why LDS landing: R10 failed because deferred inline-asm loads/stores with
// REGISTER destinations get physically reassigned by the compiler before
// the VMEM completes (it can't see pending asm ops) -> silent corruption.
// global_load_lds has NO destination registers; tokens are pre-staged to
// LDS (zero compiler VMEM in the loop); store data lives in persistent
// valr[] overwritten a full round later. The only register loads are the
// spin's (in-asm vmcnt(0), safe).
//
// Tags: dword = ((t<<2)|group)<<16 | bf16(h). Group-in-tag is required:
// zones alternate groups (zone[I&1]), so a late/stale load can only be
// detected if the group differs. Parity double buffer in global; 2-deep
// pipeline bound prevents overwrite races. Spin fallback = explicit
// sc0 sc1 register loads (always fresh) -> correctness timing-independent.

#define VOCAB 25
#define HIDDEN 512
#define BATCH 64
#define SEQ 2048
#define NSETS 4
#define HSL 32
#define RWG 128
#define NTHREADS 256
#define GDW 2048  // dwords per (parity,set,group) buffer = 16 WGs * 128

typedef short s16x8 __attribute__((ext_vector_type(8)));
typedef float f32x4 __attribute__((ext_vector_type(4)));
typedef unsigned u32x4 __attribute__((ext_vector_type(4)));
typedef unsigned long long ull;

typedef const __attribute__((address_space(1))) unsigned cglb_u32;
typedef __attribute__((address_space(3))) unsigned lds_u32;

__device__ inline unsigned short f2bf(float x) {
  unsigned u = __float_as_uint(x);
  u += 0x7fffu + ((u >> 16) & 1u);  // RNE
  return (unsigned short)(u >> 16);
}
__device__ inline float sigf(float x) { return 1.0f / (1.0f + __expf(-x)); }
__device__ inline float tanh_fast(float x) { return 2.0f / (1.0f + __expf(-2.0f * x)) - 1.0f; }

__global__ void prep_kernel(unsigned* hg, float* out) {
  const int i0 = blockIdx.x * blockDim.x + threadIdx.x;
  const int n = blockDim.x * gridDim.x;
  for (int k = i0; k < 2 * NSETS * 4 * GDW; k += n) hg[k] = 0u;  // tag 0 never matches
  if (i0 < BATCH) out[i0] = 0.f;
}

#define BUFP(PAR, GRP) (hg + ((size_t)((((PAR)*NSETS + s) * 4) + (GRP)) << 11))

// issue 4 global_load_lds_dwordx4 per wave: byte-copy of the 8KB group
// buffer into zone[SLOT]. aux=17 = SC0|SC1 (agent-coherent load).
#define GLL(G, PAR, SLOT)                                                    \
  do {                                                                       \
    const unsigned* _gb = BUFP(PAR, G);                                      \
    const char* _gp = (const char*)_gb + (wv << 12) + (lane << 4);           \
    _Pragma("unroll") for (int k_ = 0; k_ < 4; ++k_)                         \
        __builtin_amdgcn_global_load_lds(                                    \
            (cglb_u32*)(_gp + (k_ << 10)),                                   \
            (lds_u32*)&zone[SLOT][(wv << 10) + (k_ << 8)], 16, 0, 17);       \
  } while (0)

#define PHASE(I, T_, KSTR, DO_PF, DO_ST)                                     \
  do {                                                                       \
    const unsigned tu_ = (((unsigned)(T_)) << 2) | (unsigned)(I);            \
    if (tid < 128) {                                                         \
      asm volatile("s_waitcnt " KSTR ::: "memory");                          \
      __builtin_amdgcn_sched_barrier(0);                                     \
      unsigned zq[16];                                                       \
      _Pragma("unroll") for (int k_ = 0; k_ < 4; ++k_) {                     \
        const u32x4 zv = *(const u32x4*)&zone[(I) & 1][4 * tid + 512 * k_];  \
        zq[4*k_] = zv[0]; zq[4*k_+1] = zv[1];                                \
        zq[4*k_+2] = zv[2]; zq[4*k_+3] = zv[3];                              \
      }                                                                      \
      bool ok_ = true;                                                       \
      _Pragma("unroll") for (int r_ = 0; r_ < 16; ++r_)                      \
          ok_ &= ((zq[r_] >> 16) == tu_);                                    \
      if (__builtin_expect(!ok_, 0)) { /* spin: fresh register loads */      \
        const unsigned* _b = BUFP((T_) & 1, I);                              \
        u32x4 qa, qb, qc, qd;                                                \
        for (;;) {                                                           \
          asm volatile(                                                      \
              "global_load_dwordx4 %[a], %[v0], %[q] sc0 sc1\n\t"            \
              "global_load_dwordx4 %[b], %[v0], %[q] offset:2048 sc0 sc1\n\t"\
              "global_load_dwordx4 %[c], %[v1], %[q] sc0 sc1\n\t"            \
              "global_load_dwordx4 %[d], %[v1], %[q] offset:2048 sc0 sc1\n\t"\
              "s_waitcnt vmcnt(0)"                                           \
              : [a] "=&v"(qa), [b] "=&v"(qb), [c] "=&v"(qc), [d] "=&v"(qd)   \
              : [v0] "v"(sv0), [v1] "v"(sv1), [q] "s"(_b)                    \
              : "memory");                                                   \
          __builtin_amdgcn_sched_barrier(0);                                 \
          bool o2_ = true;                                                   \
          _Pragma("unroll") for (int e_ = 0; e_ < 4; ++e_) {                 \
            o2_ &= ((qa[e_] >> 16) == tu_); o2_ &= ((qb[e_] >> 16) == tu_);  \
            o2_ &= ((qc[e_] >> 16) == tu_); o2_ &= ((qd[e_] >> 16) == tu_);  \
          }                                                                  \
          if (o2_) break;                                                    \
        }                                                                    \
        _Pragma("unroll") for (int e_ = 0; e_ < 4; ++e_) {                   \
          zq[e_] = qa[e_]; zq[4+e_] = qb[e_];                                \
          zq[8+e_] = qc[e_]; zq[12+e_] = qd[e_];                             \
        }                                                                    \
      }                                                                      \
      _Pragma("unroll") for (int k_ = 0; k_ < 4; ++k_) { /* repack->hbuf */  \
        const int d0_ = 4 * tid + 512 * k_;                                  \
        const int ws_ = d0_ >> 7;                                            \
        const int cb_ = (d0_ >> 5) & 3;                                      \
        const int j_ = d0_ & 31;                                             \
        const unsigned lo_ = (zq[4*k_] & 0xffffu) | (zq[4*k_+1] << 16);      \
        const unsigned hi_ = (zq[4*k_+2] & 0xffffu) | (zq[4*k_+3] << 16);    \
        *(ull*)&hbuf[4*(I) + cb_][ws_ * 32 + j_] = (ull)lo_ | ((ull)hi_<<32);\
      }                                                                      \
    }                                                                        \
    asm volatile("s_waitcnt lgkmcnt(0)" ::: "memory");                       \
    __builtin_amdgcn_sched_barrier(0);                                       \
    __builtin_amdgcn_s_barrier();                                            \
    __builtin_amdgcn_sched_barrier(0);                                       \
    { /* MFMA over all 16 rows; group I's D rows live in quad==I */          \
      f32x4 a0a = {0.f,0.f,0.f,0.f}, a0b = {0.f,0.f,0.f,0.f};                \
      f32x4 a1a = {0.f,0.f,0.f,0.f}, a1b = {0.f,0.f,0.f,0.f};                \
      _Pragma("unroll") for (int kt = 0; kt < 16; kt += 2) {                 \
        const s16x8 A0 = *(const s16x8*)&hbuf[m16][kt * 32 + quad * 8];      \
        const s16x8 A1 = *(const s16x8*)&hbuf[m16][(kt + 1) * 32 + quad * 8];\
        a0a = __builtin_amdgcn_mfma_f32_16x16x32_bf16(A0, Bf[0][kt], a0a, 0, 0, 0);   \
        a1a = __builtin_amdgcn_mfma_f32_16x16x32_bf16(A0, Bf[1][kt], a1a, 0, 0, 0);   \
        a0b = __builtin_amdgcn_mfma_f32_16x16x32_bf16(A1, Bf[0][kt+1], a0b, 0, 0, 0); \
        a1b = __builtin_amdgcn_mfma_f32_16x16x32_bf16(A1, Bf[1][kt+1], a1b, 0, 0, 0); \
      }                                                                      \
      const f32x4 c0_ = a0a + a0b, c1_ = a1a + a1b;                          \
      if (quad == (I)) {                                                     \
        _Pragma("unroll") for (int v_ = 0; v_ < 4; ++v_) {                   \
          gatesb[v_][wv * 16 + m16] = c0_[v_];                               \
          gatesb[v_][(wv + 4) * 16 + m16] = c1_[v_];                         \
        }                                                                    \
      }                                                                      \
    }                                                                        \
    asm volatile("s_waitcnt lgkmcnt(0)" ::: "memory");                       \
    __builtin_amdgcn_sched_barrier(0);                                       \
    __builtin_amdgcn_s_barrier();                                            \
    __builtin_amdgcn_sched_barrier(0);                                       \
    if (tid < 128) {                                                         \
      if (DO_PF) { /* prefetch group (I+2)&3, 2-phase flight */              \
        const int tj_ = ((I) < 2) ? (T_) : ((T_) + 1);                       \
        GLL(((I) + 2) & 3, (tj_) & 1, (I) & 1);                              \
      }                                                                      \
      { /* cell + publish */                                                 \
        const int tok_ = (int)tokB[4 * (I) + cbc][(T_)];                     \
        const float pi_ = gatesb[cbc][jc] + xgt[tok_][jc];                   \
        const float pf_ = gatesb[cbc][32 + jc] + xgt[tok_][32 + jc];         \
        const float pg_ = gatesb[cbc][64 + jc] + xgt[tok_][64 + jc];         \
        const float po_ = gatesb[cbc][96 + jc] + xgt[tok_][96 + jc];         \
        if ((T_) < myLenv[I]) {                                              \
          const float i_ = sigf(pi_), f_ = sigf(pf_);                        \
          const float g_ = tanh_fast(pg_), o_ = sigf(po_);                   \
          cS[I] = f_ * cS[I] + i_ * g_;                                      \
          hS[I] = o_ * tanh_fast(cS[I]);                                     \
        }                                                                    \
        if (DO_ST) {                                                         \
          valr[I] = (((((unsigned)(T_) + 1u) << 2) | (unsigned)(I)) << 16) | \
                    (unsigned)f2bf(hS[I]);                                   \
          unsigned* _sb = BUFP(((T_) + 1) & 1, I);                           \
          asm volatile("global_store_dword %0, %1, %2 sc0 sc1"               \
                       :: "v"(vst), "v"(valr[I]), "s"(_sb) : "memory");      \
        }                                                                    \
      }                                                                      \
    }                                                                        \
  } while (0)

__global__ __launch_bounds__(NTHREADS, 1) void lstm_persistent(
    const int* __restrict__ tokens, const int* __restrict__ lengths,
    const float* __restrict__ W_ih, const float* __restrict__ W_hh,
    const float* __restrict__ b_ih, const float* __restrict__ b_hh,
    const float* __restrict__ fc_w, const float* __restrict__ fc_b,
    float* __restrict__ out, unsigned* hg) {
  const int tid = threadIdx.x;
  const int bid = blockIdx.x;
  // XCD-aware: set s uses blocks with bid%8 in {2s,2s+1} -> 2 XCDs/set.
  const int x = bid & 7;
  const int s = x >> 1;                       // set 0..3
  const int w = ((bid >> 3) << 1) | (x & 1);  // wg-in-set 0..15

  __shared__ __align__(16) unsigned short hbuf[16][HIDDEN + 8];  // 16 rows = 4 grp x 4 batch
  __shared__ float gatesb[4][RWG + 5];
  __shared__ float xgt[VOCAB][RWG + 5];
  __shared__ unsigned char tokB[16][SEQ];        // pre-staged tokens (bytes)
  __shared__ __align__(16) unsigned zone[2][GDW];  // gll landing zones
  __shared__ int lenAll[BATCH];
  __shared__ int order_[BATCH];
  __shared__ int gIdxS[16];
  __shared__ int gLenS[16];

  if (tid < BATCH) lenAll[tid] = lengths[tid];
  __syncthreads();
  if (tid < BATCH) {  // stable argsort(-lengths): rank by count
    const int L = lenAll[tid];
    int r = 0;
    for (int jx = 0; jx < BATCH; ++jx) {
      const int lj = lenAll[jx];
      r += ((lj > L) || (lj == L && jx < tid)) ? 1 : 0;
    }
    order_[r] = tid;
  }
  __syncthreads();
  if (tid < 16) {
    const int oi = order_[s * 16 + tid];
    gIdxS[tid] = oi;
    gLenS[tid] = lenAll[oi];
  }
  for (int i = tid; i < 16 * (HIDDEN + 8); i += NTHREADS)
    ((unsigned short*)hbuf)[i] = 0;  // h0 = 0
  for (int i = tid; i < VOCAB * RWG; i += NTHREADS) {
    const int v = i / RWG, rl = i % RWG;
    const int rg = (rl >> 5) * HIDDEN + w * HSL + (rl & 31);
    xgt[v][rl] = W_ih[rg * VOCAB + v] + b_ih[rg] + b_hh[rg];
  }
  __syncthreads();

  const int T = gLenS[0];  // set max; all 4 groups run T rounds (frozen tails)
  // pre-stage tokens for all 16 local ranks (bytes; VOCAB=25 fits)
  for (int r = 0; r < 16; ++r) {
    const int* tr = tokens + (size_t)gIdxS[r] * SEQ;
    for (int k = tid; k < T; k += NTHREADS) tokB[r][k] = (unsigned char)tr[k];
  }

  const int lane = tid & 63;
  const int wv = tid >> 6;
  const int m16 = lane & 15;
  const int quad = lane >> 4;

  // B fragments (bf16 W_hh slice) in VGPRs: wave wv owns ntiles {wv, wv+4}.
  s16x8 Bf[2][16];
#pragma unroll
  for (int nti = 0; nti < 2; ++nti) {
    const int nt = wv + 4 * nti;
    const int rl = nt * 16 + m16;  // local gate-row 0..127
    const int rg = (rl >> 5) * HIDDEN + w * HSL + (rl & 31);
    const float* wr = W_hh + (size_t)rg * HIDDEN;
#pragma unroll
    for (int kt = 0; kt < 16; ++kt) {
      const float* p = wr + kt * 32 + quad * 8;
#pragma unroll
      for (int e = 0; e < 8; ++e) Bf[nti][kt][e] = (short)f2bf(p[e]);
    }
  }

  // cell mapping (tid<128): batch cbc 0..3, unit jc 0..31 (per group)
  const int cbc = (tid >> 5) & 3;
  const int jc = tid & 31;
  int myLenv[4];
#pragma unroll
  for (int i = 0; i < 4; ++i) myLenv[i] = gLenS[4 * i + cbc];
  const unsigned sv0 = 16u * (unsigned)tid;       // spin voffsets
  const unsigned sv1 = sv0 + 4096u;
  const unsigned vst = 4u * (unsigned)(w * 128 + tid);  // producer store offset

  unsigned valr[4] = {0u, 0u, 0u, 0u};  // persistent store-data registers
  float cS[4] = {0.f, 0.f, 0.f, 0.f};
  float hS[4] = {0.f, 0.f, 0.f, 0.f};

  __syncthreads();  // tokB staged

  // ---- prologue t=0: gates are pure xgt (h0=0); publish step-1 h ----
  if (tid < 128) {
#pragma unroll
    for (int i = 0; i < 4; ++i) {
      const int tok0 = (int)tokB[4 * i + cbc][0];
      const float i_ = sigf(xgt[tok0][jc]);
      const float g_ = tanh_fast(xgt[tok0][64 + jc]);
      const float o_ = sigf(xgt[tok0][96 + jc]);
      cS[i] = i_ * g_;  // f*0 + i*g  (t=0 always < len since len>=1)
      hS[i] = o_ * tanh_fast(cS[i]);
      if (T > 1) {
        unsigned* dst = BUFP(1, i) + (w * 128 + tid);
        __hip_atomic_store(dst,
                           (((1u << 2) | (unsigned)i) << 16) | (unsigned)f2bf(hS[i]),
                           __ATOMIC_RELAXED, __HIP_MEMORY_SCOPE_AGENT);
      }
    }
  }
  __syncthreads();  // drains all VMEM: clean vmcnt stream from here

  if (T > 1) {
    // prime: polls for groups 0,1 step 1 (groups 2,3 primed inside round 1)
    if (tid < 128) {
      GLL(0, 1, 0);
      GLL(1, 1, 1);
    }
    if (T > 2) {
      // round t=1 (special counts for the prime stream)
      PHASE(0, 1, "vmcnt(4)", 1, 1);
      PHASE(1, 1, "vmcnt(5)", 1, 1);
      PHASE(2, 1, "vmcnt(6)", 1, 1);
      PHASE(3, 1, "vmcnt(6)", 1, 1);
      for (int t = 2; t <= T - 2; ++t) {  // steady
        PHASE(0, t, "vmcnt(6)", 1, 1);
        PHASE(1, t, "vmcnt(6)", 1, 1);
        PHASE(2, t, "vmcnt(6)", 1, 1);
        PHASE(3, t, "vmcnt(6)", 1, 1);
      }
    }
    {  // final round t=T-1: conservative waits, no step-T stores
      const int tf = T - 1;
      PHASE(0, tf, "vmcnt(0)", 1, 0);  // still prefetch groups 2,3 (tj=tf)
      PHASE(1, tf, "vmcnt(0)", 1, 0);
      PHASE(2, tf, "vmcnt(0)", 0, 0);
      PHASE(3, tf, "vmcnt(0)", 0, 0);
    }
  }

  // out[rank] = h . fc_w + fc_b; rank = s*16 + 4i + cbc
  if (tid < 128) {
#pragma unroll
    for (int i = 0; i < 4; ++i) {
      float part = hS[i] * fc_w[w * HSL + jc];
      part += __shfl_down(part, 16, 32);
      part += __shfl_down(part, 8, 32);
      part += __shfl_down(part, 4, 32);
      part += __shfl_down(part, 2, 32);
      part += __shfl_down(part, 1, 32);
      if (jc == 0) {
        if (w == 0) part += fc_b[0];
        atomicAdd(&out[s * 16 + 4 * i + cbc], part);
      }
    }
  }
}

extern "C" void kernel_launch(void* const* d_in, const int* in_sizes, int n_in,
                              void* d_out, int out_size, void* d_ws, size_t ws_size,
                              hipStream_t stream) {
  (void)in_sizes; (void)n_in; (void)out_size; (void)ws_size;
  const int* tokens = (const int*)d_in[0];
  const int* lengths = (const int*)d_in[1];
  const float* W_ih = (const float*)d_in[2];
  const float* W_hh = (const float*)d_in[3];
  const float* b_ih = (const float*)d_in[4];
  const float* b_hh = (const float*)d_in[5];
  const float* fc_w = (const float*)d_in[6];
  const float* fc_b = (const float*)d_in[7];
  float* out = (float*)d_out;
  unsigned* hglob = (unsigned*)d_ws;  // 256 KB: 2 parity x 4 sets x 4 groups x 8KB

  prep_kernel<<<32, 256, 0, stream>>>(hglob, out);
  lstm_persistent<<<64, NTHREADS, 0, stream>>>(tokens, lengths, W_ih, W_hh, b_ih, b_hh,
                                               fc_w, fc_b, out, hglob);
}

// Round 12
// 5554.943 us; speedup vs baseline: 2.2529x; 2.0790x over previous
//
#include <hip/hip_runtime.h>

// Packed-LSTM (B=64, S=2048, H=512, V=25) + final linear head.
// MEASURED-BEST kernel (round-2/6 structure; headline 5564 us, steady 5.42 ms).
// Sort batches by length (stable, descending) inside the kernel; 4 groups of
// 16 batches in lockstep; 16 WGs/group x 256 thr, each WG owns 32 hidden
// units (128 gate rows); W_hh slice resident in VGPRs as bf16 MFMA B-frags.
// Per step: MFMA [16x512]@[512x128], LSTM cell in fp32.
//
// Cross-WG h exchange: SELF-TAGGED qwords through LLC, wave-coalesced both
// sides. qidx = producerWG*256 + batch*16 + unitpair; each qword =
// (step_tag << 32) | (2 x bf16 h). Single-set busy-spin poll (measured best;
// dual-set, sc0/L2-local, and all stagger/prefetch variants regressed -- the
// agent-scope store->visible latency ~1.3-1.7us is the floor and any scheme
// pays it serially once per step). No flags, no release/acquire, no
// vmcnt-drain on the critical path. Parity double buffer; 2-deep pipeline
// bound prevents overwrite races (a producer reaches its t+2 store only
// after observing all t+1 tags, implying every consumer consumed t).

#define VOCAB 25
#define HIDDEN 512
#define BATCH 64
#define SEQ 2048
#define GB 16    // batches per group
#define NG 4     // groups
#define WPG 16   // workgroups per group
#define HSL 32   // hidden units per WG
#define RWG 128  // gate rows per WG = 4*HSL
#define NTHREADS 256
#define HGQ (GB * HIDDEN / 2)  // 4096 tagged qwords per group parity buffer

typedef short s16x8 __attribute__((ext_vector_type(8)));
typedef float f32x4 __attribute__((ext_vector_type(4)));

__device__ inline unsigned short f2bf(float x) {
  unsigned u = __float_as_uint(x);
  u += 0x7fffu + ((u >> 16) & 1u);  // RNE
  return (unsigned short)(u >> 16);
}
__device__ inline float sigf(float x) { return 1.0f / (1.0f + __expf(-x)); }
__device__ inline float tanh_fast(float x) { return 2.0f / (1.0f + __expf(-2.0f * x)) - 1.0f; }

__global__ void prep_kernel(unsigned long long* hg, float* out) {
  const int i = blockIdx.x * blockDim.x + threadIdx.x;
  const int n = blockDim.x * gridDim.x;
  for (int k = i; k < 2 * NG * HGQ; k += n) hg[k] = 0ull;  // tag=0: never matches t>=1
  if (i < BATCH) out[i] = 0.f;
}

__global__ __launch_bounds__(NTHREADS, 1) void lstm_persistent(
    const int* __restrict__ tokens, const int* __restrict__ lengths,
    const float* __restrict__ W_ih, const float* __restrict__ W_hh,
    const float* __restrict__ b_ih, const float* __restrict__ b_hh,
    const float* __restrict__ fc_w, const float* __restrict__ fc_b,
    float* __restrict__ out, unsigned long long* hg) {
  const int tid = threadIdx.x;
  const int bid = blockIdx.x;
  // XCD-aware swizzle: group g uses blocks with bid%8 in {2g,2g+1} -> 2 XCDs/group.
  const int x = bid & 7;
  const int g = x >> 1;                       // group 0..3
  const int w = ((bid >> 3) << 1) | (x & 1);  // wg-in-group 0..15

  __shared__ __align__(16) unsigned short hbuf[GB][HIDDEN + 8];  // bf16 h, padded
  __shared__ float gatesb[GB][RWG + 5];  // odd leading dim: cell reads 2-way (free)
  __shared__ float xgt[VOCAB][RWG + 5];  // per-slice input projection table
  __shared__ int lenAll[BATCH];
  __shared__ int order_[BATCH];
  __shared__ int gIdx[GB];
  __shared__ int gLen[GB];

  if (tid < BATCH) lenAll[tid] = lengths[tid];
  __syncthreads();
  if (tid < BATCH) {  // stable argsort(-lengths): rank by count
    const int L = lenAll[tid];
    int r = 0;
    for (int j = 0; j < BATCH; ++j) {
      const int lj = lenAll[j];
      r += ((lj > L) || (lj == L && j < tid)) ? 1 : 0;
    }
    order_[r] = tid;
  }
  __syncthreads();
  if (tid < GB) {
    const int oi = order_[g * GB + tid];
    gIdx[tid] = oi;
    gLen[tid] = lenAll[oi];
  }
  for (int i = tid; i < GB * (HIDDEN + 8); i += NTHREADS)
    ((unsigned short*)hbuf)[i] = 0;  // h0 = 0
  for (int i = tid; i < VOCAB * RWG; i += NTHREADS) {
    const int v = i / RWG, rl = i % RWG;
    const int rg = (rl >> 5) * HIDDEN + w * HSL + (rl & 31);
    xgt[v][rl] = W_ih[rg * VOCAB + v] + b_ih[rg] + b_hh[rg];
  }
  __syncthreads();

  const int T = gLen[0];  // group maxlen (sorted descending)
  const int lane = tid & 63;
  const int wv = tid >> 6;
  const int m16 = lane & 15;
  const int quad = lane >> 4;

  // B fragments (bf16 W_hh slice) resident in VGPRs: wave wv owns ntiles {wv, wv+4}.
  s16x8 Bf[2][16];
#pragma unroll
  for (int nti = 0; nti < 2; ++nti) {
    const int nt = wv + 4 * nti;
    const int rl = nt * 16 + m16;  // local gate-row 0..127
    const int rg = (rl >> 5) * HIDDEN + w * HSL + (rl & 31);
    const float* wr = W_hh + (size_t)rg * HIDDEN;
#pragma unroll
    for (int kt = 0; kt < 16; ++kt) {
      const float* p = wr + kt * 32 + quad * 8;
#pragma unroll
      for (int e = 0; e < 8; ++e) Bf[nti][kt][e] = (short)f2bf(p[e]);
    }
  }

  // Cell state: thread (cb,cs) owns hidden units jj0,jj1 of batch cb.
  const int cb = tid >> 4;
  const int cs = tid & 15;
  const int jj0 = 2 * cs, jj1 = 2 * cs + 1;
  const int myLen = gLen[cb];
  const int* tokRow = tokens + (size_t)gIdx[cb] * SEQ;
  unsigned long long* const base0 = hg + (size_t)g * HGQ;         // parity 0
  unsigned long long* const base1 = hg + (size_t)(NG + g) * HGQ;  // parity 1

  float c0 = 0.f, c1 = 0.f, h0 = 0.f, h1 = 0.f;

  for (int t = 0; t < T; ++t) {
    const int tok = tokRow[t];  // L1-hit broadcast; issued before the poll

    if (t > 0) {
      // Busy-spin poll of self-tagged h words for step t (parity t&1).
      // Load r reads producer r's qword for (batch=tid>>4, unitpair=tid&15):
      // address r*256 + tid -> 512 B contiguous per wave per load.
      const unsigned long long* src = ((t & 1) ? base1 : base0) + tid;
      unsigned long long q[16];
      for (;;) {
        bool ok = true;
#pragma unroll
        for (int r = 0; r < 16; ++r)
          q[r] = __hip_atomic_load(src + r * 256, __ATOMIC_RELAXED,
                                   __HIP_MEMORY_SCOPE_AGENT);
#pragma unroll
        for (int r = 0; r < 16; ++r) ok &= ((unsigned)(q[r] >> 32) == (unsigned)t);
        if (ok) break;
      }
      // Scatter payloads into LDS: producer r's units r*32+2cs, r*32+2cs+1.
#pragma unroll
      for (int r = 0; r < 16; ++r)
        *(unsigned*)&hbuf[cb][r * 32 + jj0] = (unsigned)q[r];
    }
    __syncthreads();  // hbuf[t] staged

    // gates slice = h[16x512] @ Wslice^T[512x128] via MFMA 16x16x32 bf16.
    // Even/odd kt split: two 8-deep dependent chains per accumulator.
    f32x4 acc0a = {0.f, 0.f, 0.f, 0.f}, acc0b = {0.f, 0.f, 0.f, 0.f};
    f32x4 acc1a = {0.f, 0.f, 0.f, 0.f}, acc1b = {0.f, 0.f, 0.f, 0.f};
#pragma unroll
    for (int kt = 0; kt < 16; kt += 2) {
      const s16x8 A0 = *(const s16x8*)&hbuf[m16][kt * 32 + quad * 8];
      const s16x8 A1 = *(const s16x8*)&hbuf[m16][(kt + 1) * 32 + quad * 8];
      acc0a = __builtin_amdgcn_mfma_f32_16x16x32_bf16(A0, Bf[0][kt], acc0a, 0, 0, 0);
      acc1a = __builtin_amdgcn_mfma_f32_16x16x32_bf16(A0, Bf[1][kt], acc1a, 0, 0, 0);
      acc0b = __builtin_amdgcn_mfma_f32_16x16x32_bf16(A1, Bf[0][kt + 1], acc0b, 0, 0, 0);
      acc1b = __builtin_amdgcn_mfma_f32_16x16x32_bf16(A1, Bf[1][kt + 1], acc1b, 0, 0, 0);
    }
    const f32x4 acc0 = acc0a + acc0b;
    const f32x4 acc1 = acc1a + acc1b;
    // D layout: col(n)=lane&15, row(m)=quad*4+v
#pragma unroll
    for (int v = 0; v < 4; ++v) {
      gatesb[quad * 4 + v][wv * 16 + m16] = acc0[v];
      gatesb[quad * 4 + v][(wv + 4) * 16 + m16] = acc1[v];
    }
    __syncthreads();  // gates ready; also fences hbuf reads vs next-iter staging

    // LSTM cell update (fp32), frozen past sequence end
    const float pi0 = gatesb[cb][jj0] + xgt[tok][jj0];
    const float pf0 = gatesb[cb][32 + jj0] + xgt[tok][32 + jj0];
    const float pg0 = gatesb[cb][64 + jj0] + xgt[tok][64 + jj0];
    const float po0 = gatesb[cb][96 + jj0] + xgt[tok][96 + jj0];
    const float pi1 = gatesb[cb][jj1] + xgt[tok][jj1];
    const float pf1 = gatesb[cb][32 + jj1] + xgt[tok][32 + jj1];
    const float pg1 = gatesb[cb][64 + jj1] + xgt[tok][64 + jj1];
    const float po1 = gatesb[cb][96 + jj1] + xgt[tok][96 + jj1];
    if (t < myLen) {
      const float i0 = sigf(pi0), f0 = sigf(pf0), g0 = tanh_fast(pg0), o0 = sigf(po0);
      c0 = f0 * c0 + i0 * g0;
      h0 = o0 * tanh_fast(c0);
      const float i1 = sigf(pi1), f1 = sigf(pf1), g1 = tanh_fast(pg1), o1 = sigf(po1);
      c1 = f1 * c1 + i1 * g1;
      h1 = o1 * tanh_fast(c1);
    }
    if (t + 1 < T) {  // publish h for step t+1: single self-tagged relaxed qword.
      // Layout: w*256 + tid -> producer WG's stores are 512 B contiguous/wave.
      const unsigned payload = (unsigned)f2bf(h0) | ((unsigned)f2bf(h1) << 16);
      const unsigned long long qv = ((unsigned long long)(unsigned)(t + 1) << 32) | payload;
      unsigned long long* hp = (((t + 1) & 1) ? base1 : base0) + w * 256 + tid;
      __hip_atomic_store(hp, qv, __ATOMIC_RELAXED, __HIP_MEMORY_SCOPE_AGENT);
    }
    // no end-of-step barrier needed: next-iter hbuf writes are fenced by the
    // gates __syncthreads above; gatesb reads complete before next-iter sync.
  }

  // out[p] = h . fc_w + fc_b, p = sorted position
  float part = h0 * fc_w[w * HSL + jj0] + h1 * fc_w[w * HSL + jj1];
  part += __shfl_down(part, 8, 16);
  part += __shfl_down(part, 4, 16);
  part += __shfl_down(part, 2, 16);
  part += __shfl_down(part, 1, 16);
  if (cs == 0) {
    if (w == 0) part += fc_b[0];
    atomicAdd(&out[g * GB + cb], part);
  }
}

extern "C" void kernel_launch(void* const* d_in, const int* in_sizes, int n_in,
                              void* d_out, int out_size, void* d_ws, size_t ws_size,
                              hipStream_t stream) {
  (void)in_sizes; (void)n_in; (void)out_size; (void)ws_size;
  const int* tokens = (const int*)d_in[0];
  const int* lengths = (const int*)d_in[1];
  const float* W_ih = (const float*)d_in[2];
  const float* W_hh = (const float*)d_in[3];
  const float* b_ih = (const float*)d_in[4];
  const float* b_hh = (const float*)d_in[5];
  const float* fc_w = (const float*)d_in[6];
  const float* fc_b = (const float*)d_in[7];
  float* out = (float*)d_out;
  unsigned long long* hglob = (unsigned long long*)d_ws;  // 256 KB tagged h double-buffer

  prep_kernel<<<32, 256, 0, stream>>>(hglob, out);
  lstm_persistent<<<64, NTHREADS, 0, stream>>>(tokens, lengths, W_ih, W_hh, b_ih, b_hh,
                                               fc_w, fc_b, out, hglob);
}

// Round 13
// 5247.026 us; speedup vs baseline: 2.3851x; 1.0587x over previous
//
#include <hip/hip_runtime.h>

// Packed-LSTM (B=64, S=2048, H=512, V=25) + final linear head.
// R12 structure (measured best 5.55 ms) + XCD-LOCAL L2 exchange retry with a
// CONTENTION-FREE poll. 4 groups of 16 batches; 16 WGs/group x 256 thr; WG
// owns 32 hidden units (128 gate rows); W_hh slice in VGPRs as bf16 MFMA
// B-frags. Per step: MFMA [16x512]@[512x128], LSTM cell in fp32.
//
// Exchange: self-tagged qwords ((t<<32)|2xbf16), parity double buffer.
//  - Grid 128; group g = blocks with bid%8==2g (odd residues exit). Under
//    the round-robin block->XCD mapping (supported by T1's measured %8
//    swizzle effect) each group is XCD-local; roll-call via HW_REG_XCC_ID
//    verifies, else pure agent mode.
//  - L2 mode: producers store sc0 (lands in own XCD L2, RT ~0.2us) AND
//    agent-store (serves demoted consumers). Consumers run a LIGHT
//    REPRESENTATIVE POLL: 1 sc0 load/thread/iter (16x less L2 traffic than
//    R5's failed 16-wide poll, which oversubscribed L2 ~3x), s_sleep(1)
//    throttled; on rep tag-hit, one full 16-load sc0 fetch (producers store
//    near-simultaneously -> usually 1 iter).
//  - Budgets (wave-uniform via __all) -> sticky demote to the agent path
//    (R2 protocol, always correct). Equality tags + 2-deep pipeline bound
//    prevent overwrite races on both buffers; worst case = agent + ~0.25ms.

#define VOCAB 25
#define HIDDEN 512
#define BATCH 64
#define SEQ 2048
#define GB 16    // batches per group
#define NG 4     // groups
#define WPG 16   // workgroups per group
#define HSL 32   // hidden units per WG
#define RWG 128  // gate rows per WG = 4*HSL
#define NTHREADS 256
#define HGQ (GB * HIDDEN / 2)  // 4096 tagged qwords per group parity buffer
#define RC_INTS 1024           // 4 KB roll-call region
#define REP_BUDGET 1024        // rep-poll iters before demote (per step)
#define FF_BUDGET 256          // full-fetch iters before demote

typedef short s16x8 __attribute__((ext_vector_type(8)));
typedef float f32x4 __attribute__((ext_vector_type(4)));
typedef unsigned long long ull;

__device__ inline unsigned short f2bf(float x) {
  unsigned u = __float_as_uint(x);
  u += 0x7fffu + ((u >> 16) & 1u);  // RNE
  return (unsigned short)(u >> 16);
}
__device__ inline float sigf(float x) { return 1.0f / (1.0f + __expf(-x)); }
__device__ inline float tanh_fast(float x) { return 2.0f / (1.0f + __expf(-2.0f * x)) - 1.0f; }

__global__ void prep_kernel(int* rc, ull* hgA, ull* hgL, int allow_l2, float* out) {
  const int i = blockIdx.x * blockDim.x + threadIdx.x;
  const int n = blockDim.x * gridDim.x;
  for (int k = i; k < RC_INTS; k += n) rc[k] = 0;
  for (int k = i; k < 2 * NG * HGQ; k += n) hgA[k] = 0ull;  // tag 0 never matches
  if (allow_l2)
    for (int k = i; k < 2 * NG * HGQ; k += n) hgL[k] = 0ull;
  if (i < BATCH) out[i] = 0.f;
}

__global__ __launch_bounds__(NTHREADS, 1) void lstm_persistent(
    const int* __restrict__ tokens, const int* __restrict__ lengths,
    const float* __restrict__ W_ih, const float* __restrict__ W_hh,
    const float* __restrict__ b_ih, const float* __restrict__ b_hh,
    const float* __restrict__ fc_w, const float* __restrict__ fc_b,
    float* __restrict__ out, int* rc, ull* hgA, ull* hgL, int allow_l2) {
  const int tid = threadIdx.x;
  const int bid = blockIdx.x;
  const int x = bid & 7;
  if (x & 1) return;       // odd residues idle (placement spacer)
  const int g = x >> 1;    // group 0..3 -> residue 2g -> one XCD if RR holds
  const int w = bid >> 3;  // wg-in-group 0..15

  __shared__ __align__(16) unsigned short hbuf[GB][HIDDEN + 8];  // bf16 h, padded
  __shared__ float gatesb[GB][RWG + 5];
  __shared__ float xgt[VOCAB][RWG + 5];
  __shared__ int lenAll[BATCH];
  __shared__ int order_[BATCH];
  __shared__ int gIdx[GB];
  __shared__ int gLen[GB];
  __shared__ int rcsh[WPG];

  // publish roll-call entry early (overlaps init)
  unsigned xcc;
  asm volatile("s_getreg_b32 %0, hwreg(20, 0, 32)" : "=s"(xcc));  // HW_REG_XCC_ID
  xcc &= 0xFu;
  if (tid == 0)
    __hip_atomic_store(&rc[g * WPG + w], (int)(0x100u | xcc), __ATOMIC_RELAXED,
                       __HIP_MEMORY_SCOPE_AGENT);

  if (tid < BATCH) lenAll[tid] = lengths[tid];
  __syncthreads();
  if (tid < BATCH) {  // stable argsort(-lengths): rank by count
    const int L = lenAll[tid];
    int r = 0;
    for (int j = 0; j < BATCH; ++j) {
      const int lj = lenAll[j];
      r += ((lj > L) || (lj == L && j < tid)) ? 1 : 0;
    }
    order_[r] = tid;
  }
  __syncthreads();
  if (tid < GB) {
    const int oi = order_[g * GB + tid];
    gIdx[tid] = oi;
    gLen[tid] = lenAll[oi];
  }
  for (int i = tid; i < GB * (HIDDEN + 8); i += NTHREADS)
    ((unsigned short*)hbuf)[i] = 0;  // h0 = 0
  for (int i = tid; i < VOCAB * RWG; i += NTHREADS) {
    const int v = i / RWG, rl = i % RWG;
    const int rg = (rl >> 5) * HIDDEN + w * HSL + (rl & 31);
    xgt[v][rl] = W_ih[rg * VOCAB + v] + b_ih[rg] + b_hh[rg];
  }

  // roll-call gather: all 16 members' XCC ids
  if (tid < WPG) {
    int v;
    do {
      v = __hip_atomic_load(&rc[g * WPG + tid], __ATOMIC_RELAXED,
                            __HIP_MEMORY_SCOPE_AGENT);
    } while (!(v & 0x100));
    rcsh[tid] = v & 0xF;
  }
  __syncthreads();
  bool uni = true;
#pragma unroll
  for (int j = 0; j < WPG; ++j) uni &= (rcsh[j] == rcsh[0]);
  const bool l2grp = uni && (allow_l2 != 0);

  const int T = gLen[0];  // group maxlen (sorted descending)
  const int lane = tid & 63;
  const int wv = tid >> 6;
  const int m16 = lane & 15;
  const int quad = lane >> 4;

  // B fragments (bf16 W_hh slice) in VGPRs: wave wv owns ntiles {wv, wv+4}.
  s16x8 Bf[2][16];
#pragma unroll
  for (int nti = 0; nti < 2; ++nti) {
    const int nt = wv + 4 * nti;
    const int rl = nt * 16 + m16;  // local gate-row 0..127
    const int rg = (rl >> 5) * HIDDEN + w * HSL + (rl & 31);
    const float* wr = W_hh + (size_t)rg * HIDDEN;
#pragma unroll
    for (int kt = 0; kt < 16; ++kt) {
      const float* p = wr + kt * 32 + quad * 8;
#pragma unroll
      for (int e = 0; e < 8; ++e) Bf[nti][kt][e] = (short)f2bf(p[e]);
    }
  }

  // Cell state: thread (cb,cs) owns hidden units jj0,jj1 of batch cb.
  const int cb = tid >> 4;
  const int cs = tid & 15;
  const int jj0 = 2 * cs, jj1 = 2 * cs + 1;
  const int myLen = gLen[cb];
  const int* tokRow = tokens + (size_t)gIdx[cb] * SEQ;
  ull* const baseA0 = hgA + (size_t)g * HGQ;         // agent parity 0
  ull* const baseA1 = hgA + (size_t)(NG + g) * HGQ;  // agent parity 1
  ull* const l2b0 = hgL + (size_t)g * HGQ;           // L2 parity 0
  ull* const l2b1 = hgL + (size_t)(NG + g) * HGQ;    // L2 parity 1

  // poll voffsets: vo[j] covers producers r=2j (imm 0), r=2j+1 (imm 2048)
  unsigned vo[8];
#pragma unroll
  for (int j = 0; j < 8; ++j) vo[j] = (unsigned)(tid * 8 + j * 4096);
  const int rep = (w + 8) & 15;  // fixed non-self representative producer
  const unsigned voRep = (unsigned)((rep * 256 + tid) * 8);
  const unsigned voS = (unsigned)((w * 256 + tid) * 8);  // producer store offset

  bool l2m = l2grp;  // consumer path (sticky-demotable, wave-uniform)
  float c0 = 0.f, c1 = 0.f, h0 = 0.f, h1 = 0.f;

  for (int t = 0; t < T; ++t) {
    const int tok = tokRow[t];  // issued before the poll; latency hidden

    if (t > 0) {
      ull q[16];
      bool got = false;
      if (l2m) {
        const ull* lb = (t & 1) ? l2b1 : l2b0;
        // light representative poll: 1 sc0 load per thread per iteration
        bool hit = false;
        int iters = 0;
        for (;;) {
          ull rq;
          asm volatile(
              "global_load_dwordx2 %0, %1, %2 sc0\n\t"
              "s_waitcnt vmcnt(0)"
              : "=&v"(rq) : "v"(voRep), "s"(lb) : "memory");
          __builtin_amdgcn_sched_barrier(0);
          if (__all((unsigned)(rq >> 32) == (unsigned)t)) { hit = true; break; }
          if (++iters > REP_BUDGET) break;
          __builtin_amdgcn_s_sleep(1);
        }
        if (hit) {  // full fetch (usually 1 iteration)
          int fi = 0;
          for (;;) {
            asm volatile(
                "global_load_dwordx2 %[q0],  %[o0], %[b] sc0\n\t"
                "global_load_dwordx2 %[q1],  %[o0], %[b] offset:2048 sc0\n\t"
                "global_load_dwordx2 %[q2],  %[o1], %[b] sc0\n\t"
                "global_load_dwordx2 %[q3],  %[o1], %[b] offset:2048 sc0\n\t"
                "global_load_dwordx2 %[q4],  %[o2], %[b] sc0\n\t"
                "global_load_dwordx2 %[q5],  %[o2], %[b] offset:2048 sc0\n\t"
                "global_load_dwordx2 %[q6],  %[o3], %[b] sc0\n\t"
                "global_load_dwordx2 %[q7],  %[o3], %[b] offset:2048 sc0\n\t"
                "global_load_dwordx2 %[q8],  %[o4], %[b] sc0\n\t"
                "global_load_dwordx2 %[q9],  %[o4], %[b] offset:2048 sc0\n\t"
                "global_load_dwordx2 %[q10], %[o5], %[b] sc0\n\t"
                "global_load_dwordx2 %[q11], %[o5], %[b] offset:2048 sc0\n\t"
                "global_load_dwordx2 %[q12], %[o6], %[b] sc0\n\t"
                "global_load_dwordx2 %[q13], %[o6], %[b] offset:2048 sc0\n\t"
                "global_load_dwordx2 %[q14], %[o7], %[b] sc0\n\t"
                "global_load_dwordx2 %[q15], %[o7], %[b] offset:2048 sc0\n\t"
                "s_waitcnt vmcnt(0)"
                : [q0] "=&v"(q[0]), [q1] "=&v"(q[1]), [q2] "=&v"(q[2]),
                  [q3] "=&v"(q[3]), [q4] "=&v"(q[4]), [q5] "=&v"(q[5]),
                  [q6] "=&v"(q[6]), [q7] "=&v"(q[7]), [q8] "=&v"(q[8]),
                  [q9] "=&v"(q[9]), [q10] "=&v"(q[10]), [q11] "=&v"(q[11]),
                  [q12] "=&v"(q[12]), [q13] "=&v"(q[13]), [q14] "=&v"(q[14]),
                  [q15] "=&v"(q[15])
                : [o0] "v"(vo[0]), [o1] "v"(vo[1]), [o2] "v"(vo[2]),
                  [o3] "v"(vo[3]), [o4] "v"(vo[4]), [o5] "v"(vo[5]),
                  [o6] "v"(vo[6]), [o7] "v"(vo[7]), [b] "s"(lb)
                : "memory");
            __builtin_amdgcn_sched_barrier(0);
            bool ok = true;
#pragma unroll
            for (int r = 0; r < 16; ++r)
              ok &= ((unsigned)(q[r] >> 32) == (unsigned)t);
            if (__all(ok)) { got = true; break; }
            if (++fi > FF_BUDGET) break;
            __builtin_amdgcn_s_sleep(1);
          }
        }
        if (!got) l2m = false;  // sticky, wave-uniform demotion
      }
      if (!got) {
        // agent-scope spin (R2 protocol; always correct)
        const ull* src = ((t & 1) ? baseA1 : baseA0) + tid;
        for (;;) {
          bool ok = true;
#pragma unroll
          for (int r = 0; r < 16; ++r)
            q[r] = __hip_atomic_load(src + r * 256, __ATOMIC_RELAXED,
                                     __HIP_MEMORY_SCOPE_AGENT);
#pragma unroll
          for (int r = 0; r < 16; ++r)
            ok &= ((unsigned)(q[r] >> 32) == (unsigned)t);
          if (ok) break;
        }
      }
      // Scatter payloads into LDS: producer r's units r*32+2cs, r*32+2cs+1.
#pragma unroll
      for (int r = 0; r < 16; ++r)
        *(unsigned*)&hbuf[cb][r * 32 + jj0] = (unsigned)q[r];
    }
    __syncthreads();  // hbuf[t] staged

    // gates slice = h[16x512] @ Wslice^T[512x128] via MFMA 16x16x32 bf16.
    f32x4 acc0a = {0.f, 0.f, 0.f, 0.f}, acc0b = {0.f, 0.f, 0.f, 0.f};
    f32x4 acc1a = {0.f, 0.f, 0.f, 0.f}, acc1b = {0.f, 0.f, 0.f, 0.f};
#pragma unroll
    for (int kt = 0; kt < 16; kt += 2) {
      const s16x8 A0 = *(const s16x8*)&hbuf[m16][kt * 32 + quad * 8];
      const s16x8 A1 = *(const s16x8*)&hbuf[m16][(kt + 1) * 32 + quad * 8];
      acc0a = __builtin_amdgcn_mfma_f32_16x16x32_bf16(A0, Bf[0][kt], acc0a, 0, 0, 0);
      acc1a = __builtin_amdgcn_mfma_f32_16x16x32_bf16(A0, Bf[1][kt], acc1a, 0, 0, 0);
      acc0b = __builtin_amdgcn_mfma_f32_16x16x32_bf16(A1, Bf[0][kt + 1], acc0b, 0, 0, 0);
      acc1b = __builtin_amdgcn_mfma_f32_16x16x32_bf16(A1, Bf[1][kt + 1], acc1b, 0, 0, 0);
    }
    const f32x4 acc0 = acc0a + acc0b;
    const f32x4 acc1 = acc1a + acc1b;
    // D layout: col(n)=lane&15, row(m)=quad*4+v
#pragma unroll
    for (int v = 0; v < 4; ++v) {
      gatesb[quad * 4 + v][wv * 16 + m16] = acc0[v];
      gatesb[quad * 4 + v][(wv + 4) * 16 + m16] = acc1[v];
    }
    __syncthreads();  // gates ready; also fences hbuf reads vs next-iter staging

    // LSTM cell update (fp32), frozen past sequence end
    const float pi0 = gatesb[cb][jj0] + xgt[tok][jj0];
    const float pf0 = gatesb[cb][32 + jj0] + xgt[tok][32 + jj0];
    const float pg0 = gatesb[cb][64 + jj0] + xgt[tok][64 + jj0];
    const float po0 = gatesb[cb][96 + jj0] + xgt[tok][96 + jj0];
    const float pi1 = gatesb[cb][jj1] + xgt[tok][jj1];
    const float pf1 = gatesb[cb][32 + jj1] + xgt[tok][32 + jj1];
    const float pg1 = gatesb[cb][64 + jj1] + xgt[tok][64 + jj1];
    const float po1 = gatesb[cb][96 + jj1] + xgt[tok][96 + jj1];
    if (t < myLen) {
      const float i0 = sigf(pi0), f0 = sigf(pf0), g0 = tanh_fast(pg0), o0 = sigf(po0);
      c0 = f0 * c0 + i0 * g0;
      h0 = o0 * tanh_fast(c0);
      const float i1 = sigf(pi1), f1 = sigf(pf1), g1 = tanh_fast(pg1), o1 = sigf(po1);
      c1 = f1 * c1 + i1 * g1;
      h1 = o1 * tanh_fast(c1);
    }
    if (t + 1 < T) {  // publish h for step t+1: tagged qword, dual path
      const unsigned payload = (unsigned)f2bf(h0) | ((unsigned)f2bf(h1) << 16);
      const ull qv = ((ull)(unsigned)(t + 1) << 32) | payload;
      if (l2grp) {  // fast path: sc0 store stays in this XCD's L2
        const ull* ldst = (((t + 1) & 1) ? l2b1 : l2b0);
        asm volatile("global_store_dwordx2 %0, %1, %2 sc0"
                     :: "v"(voS), "v"(qv), "s"(ldst) : "memory");
      }
      ull* hp = (((t + 1) & 1) ? baseA1 : baseA0) + w * 256 + tid;
      __hip_atomic_store(hp, qv, __ATOMIC_RELAXED, __HIP_MEMORY_SCOPE_AGENT);
    }
  }

  // out[p] = h . fc_w + fc_b, p = sorted position
  float part = h0 * fc_w[w * HSL + jj0] + h1 * fc_w[w * HSL + jj1];
  part += __shfl_down(part, 8, 16);
  part += __shfl_down(part, 4, 16);
  part += __shfl_down(part, 2, 16);
  part += __shfl_down(part, 1, 16);
  if (cs == 0) {
    if (w == 0) part += fc_b[0];
    atomicAdd(&out[g * GB + cb], part);
  }
}

extern "C" void kernel_launch(void* const* d_in, const int* in_sizes, int n_in,
                              void* d_out, int out_size, void* d_ws, size_t ws_size,
                              hipStream_t stream) {
  (void)in_sizes; (void)n_in; (void)out_size;
  const int* tokens = (const int*)d_in[0];
  const int* lengths = (const int*)d_in[1];
  const float* W_ih = (const float*)d_in[2];
  const float* W_hh = (const float*)d_in[3];
  const float* b_ih = (const float*)d_in[4];
  const float* b_hh = (const float*)d_in[5];
  const float* fc_w = (const float*)d_in[6];
  const float* fc_b = (const float*)d_in[7];
  float* out = (float*)d_out;

  // workspace layout: [4KB rollcall][256KB agent hg][256KB L2 hg]
  int* rc = (int*)d_ws;
  ull* hgA = (ull*)((char*)d_ws + 4096);
  ull* hgL = (ull*)((char*)d_ws + 4096 + 2 * NG * HGQ * sizeof(ull));
  const int allow_l2 = (ws_size >= 4096 + 4ull * NG * HGQ * sizeof(ull)) ? 1 : 0;

  prep_kernel<<<32, 256, 0, stream>>>(rc, hgA, hgL, allow_l2, out);
  lstm_persistent<<<128, NTHREADS, 0, stream>>>(tokens, lengths, W_ih, W_hh, b_ih,
                                                b_hh, fc_w, fc_b, out, rc, hgA, hgL,
                                                allow_l2);
}